// Round 29
// baseline (348.694 us; speedup 1.0000x reference)
//
#include <hip/hip_runtime.h>
#include <cstdint>

#define HID 2048
#define SLEN 2048
#define NH 8
#define HD 256
#define MTOT 4096

constexpr float SCALING = 0.0625f;   // 256^-0.5
constexpr float SOFTCAP = 50.0f;

typedef __attribute__((ext_vector_type(8))) short short8;
typedef __attribute__((ext_vector_type(4))) float f32x4;

__device__ __forceinline__ uint16_t bfhi(float x) {
  return (uint16_t)(__float_as_uint(x) >> 16);           // truncate
}
__device__ __forceinline__ float bf2f(uint16_t h) {
  return __uint_as_float((uint32_t)h << 16);
}
__device__ __forceinline__ void packsplit8(const float4 a, const float4 b,
                                           short8& hi, short8& lo) {
  const float x[8] = {a.x, a.y, a.z, a.w, b.x, b.y, b.z, b.w};
  #pragma unroll
  for (int i = 0; i < 8; ++i) {
    const uint32_t u = __float_as_uint(x[i]);
    const uint16_t h = (uint16_t)(u >> 16);
    const float r = x[i] - bf2f(h);
    hi[i] = (short)h;
    lo[i] = (short)(__float_as_uint(r) >> 16);
  }
}
__device__ __forceinline__ void packhi8(const float4 a, const float4 b, short8& hi) {
  hi[0] = (short)bfhi(a.x); hi[1] = (short)bfhi(a.y);
  hi[2] = (short)bfhi(a.z); hi[3] = (short)bfhi(a.w);
  hi[4] = (short)bfhi(b.x); hi[5] = (short)bfhi(b.y);
  hi[6] = (short)bfhi(b.z); hi[7] = (short)bfhi(b.w);
}
__device__ __forceinline__ void atomAddF(float* p, float v) {
  __hip_atomic_fetch_add(p, v, __ATOMIC_RELAXED, __HIP_MEMORY_SCOPE_AGENT);
}
__device__ __forceinline__ uint32_t packbf2(float x0, float x1) {
  return (uint32_t)bfhi(x0) | ((uint32_t)bfhi(x1) << 16);
}

// ---------- conv_pre v2 (validated r27): hs -> split; weights -> bf16 frag-native -----
__global__ __launch_bounds__(256) void conv_pre(
    const float* __restrict__ hs,
    const float* __restrict__ WBq, const float* __restrict__ WBk,
    const float* __restrict__ WBv,
    const float* __restrict__ WAq, const float* __restrict__ WAk,
    const float* __restrict__ WAv,
    uint16_t* __restrict__ hsh, uint16_t* __restrict__ hsl,
    uint16_t* __restrict__ wfh) {
  const int bid = blockIdx.x;
  const int tid = threadIdx.x;
  if (bid < 4096) {
    const size_t off = (size_t)bid * 2048 + tid * 8;
    const float4 a = *(const float4*)&hs[off];
    const float4 b = *(const float4*)&hs[off + 4];
    short8 hi, lo;
    packsplit8(a, b, hi, lo);
    *(short8*)&hsh[off] = hi;
    *(short8*)&hsl[off] = lo;
  } else {
    const int g = (bid - 4096) * 256 + tid;   // 0..688127
    const int lane_ = g & 63;
    const int cf = (g >> 6) & 7;
    const int kc = (g >> 9) & 63;
    const int ct = g >> 15;                   // 0..20
    const int col = cf * 16 + (lane_ & 15);
    const int kb = kc * 32 + 8 * (lane_ >> 4);
    float x[8];
    #pragma unroll
    for (int e = 0; e < 8; ++e) {
      const int k = kb + e;
      float v;
      if (ct == 12) {
        if (col < 48)      v = WAq[(size_t)k * 48 + col];
        else if (col < 64) v = WAk[(size_t)k * 16 + (col - 48)];
        else if (col < 80) v = WAv[(size_t)k * 16 + (col - 64)];
        else               v = 0.f;
      } else if (ct < 12) {
        v = WBq[(size_t)k * 1536 + ct * 128 + col];
      } else if (ct < 17) {
        v = WBk[(size_t)k * 512 + (ct - 13) * 128 + col];
      } else {
        v = WBv[(size_t)k * 512 + (ct - 17) * 128 + col];
      }
      x[e] = v;
    }
    short8 hi;
    packhi8(make_float4(x[0], x[1], x[2], x[3]),
            make_float4(x[4], x[5], x[6], x[7]), hi);
    *(short8*)&wfh[(size_t)g * 8] = hi;
  }
}

// ---------- gemm_proj v6 (validated r28): BK=64, 2-term split -------------------------
__global__ __launch_bounds__(256) void gemm_proj(
    const uint16_t* __restrict__ hsh, const uint16_t* __restrict__ hsl,
    const uint16_t* __restrict__ wfh,
    float* __restrict__ Cq, float* __restrict__ Ck, float* __restrict__ Cv,
    float* __restrict__ Aout) {
  __shared__ uint16_t Ah[16 * 520], Al[16 * 520], Bh[16 * 520];
  const int tid = threadIdx.x;
  const int bid = blockIdx.x;          // 0..671
  const int work = (bid & 7) * 84 + (bid >> 3);
  const int ct = work % 21;
  const int row0 = (work / 21) * 128;
  const bool special = (ct == 12);
  float* Cmat = Cq; int Nseg = 1536; int col0 = ct * 128;
  if (ct >= 17)      { Cmat = Cv; Nseg = 512; col0 = (ct - 17) * 128; }
  else if (ct >= 13) { Cmat = Ck; Nseg = 512; col0 = (ct - 13) * 128; }
  const int lane = tid & 63;
  const int wv = tid >> 6;
  const int wr = wv >> 1, wc = wv & 1;

  f32x4 acc[4][4];
  #pragma unroll
  for (int m = 0; m < 4; ++m)
    #pragma unroll
    for (int n = 0; n < 4; ++n) acc[m][n] = (f32x4){0.f, 0.f, 0.f, 0.f};

  const int ar = tid >> 1;             // A row 0..127
  const int akb = (tid & 1) * 16;      // k half within chunk
  const int ia0 = (ar >> 4) * 520 + (ar & 15) * 8 + (akb >> 3) * 128;
  const int bf_ = tid >> 5;            // B copy frag 0..7
  const int boff = (tid & 31) * 16;    // 0..496
  const int ib = bf_ * 520 + boff;

  for (int kc2 = 0; kc2 < 32; ++kc2) {
    short8 a_h[2][2], a_l[2][2], b_h[2][2];
    #pragma unroll
    for (int c2 = 0; c2 < 2; ++c2) {
      const size_t aoff = (size_t)(row0 + ar) * 2048 + kc2 * 64 + c2 * 32 + akb;
      a_h[c2][0] = *(const short8*)&hsh[aoff];
      a_h[c2][1] = *(const short8*)&hsh[aoff + 8];
      a_l[c2][0] = *(const short8*)&hsl[aoff];
      a_l[c2][1] = *(const short8*)&hsl[aoff + 8];
      const size_t boffg = ((size_t)(ct * 64 + kc2 * 2 + c2) * 8 + bf_) * 512 + boff;
      b_h[c2][0] = *(const short8*)&wfh[boffg];
      b_h[c2][1] = *(const short8*)&wfh[boffg + 8];
    }
    __syncthreads();   // previous tile fully consumed
    #pragma unroll
    for (int c2 = 0; c2 < 2; ++c2) {
      const int fa = c2 * 8 * 520;
      *(short8*)&Ah[fa + ia0] = a_h[c2][0];  *(short8*)&Ah[fa + ia0 + 128] = a_h[c2][1];
      *(short8*)&Al[fa + ia0] = a_l[c2][0];  *(short8*)&Al[fa + ia0 + 128] = a_l[c2][1];
      *(short8*)&Bh[fa + ib] = b_h[c2][0];   *(short8*)&Bh[fa + ib + 8] = b_h[c2][1];
    }
    __syncthreads();
    #pragma unroll
    for (int c2 = 0; c2 < 2; ++c2) {
      const int fb = c2 * 8;
      short8 bhf[4];
      #pragma unroll
      for (int nf = 0; nf < 4; ++nf)
        bhf[nf] = *(const short8*)&Bh[(fb + wc * 4 + nf) * 520 + lane * 8];
      #pragma unroll
      for (int m = 0; m < 4; ++m) {
        const short8 ahf = *(const short8*)&Ah[(fb + wr * 4 + m) * 520 + lane * 8];
        const short8 alf = *(const short8*)&Al[(fb + wr * 4 + m) * 520 + lane * 8];
        #pragma unroll
        for (int nf = 0; nf < 4; ++nf) {
          acc[m][nf] = __builtin_amdgcn_mfma_f32_16x16x32_bf16(ahf, bhf[nf], acc[m][nf], 0, 0, 0);
          acc[m][nf] = __builtin_amdgcn_mfma_f32_16x16x32_bf16(alf, bhf[nf], acc[m][nf], 0, 0, 0);
        }
      }
    }
  }
  #pragma unroll
  for (int m = 0; m < 4; ++m)
    #pragma unroll
    for (int nf = 0; nf < 4; ++nf) {
      const int row = row0 + wr * 64 + m * 16 + ((lane >> 4) << 2);
      const int col = wc * 64 + nf * 16 + (lane & 15);
      if (!special) {
        #pragma unroll
        for (int ri = 0; ri < 4; ++ri)
          Cmat[(size_t)(row + ri) * Nseg + col0 + col] = acc[m][nf][ri];
      } else if (col < 80) {
        #pragma unroll
        for (int ri = 0; ri < 4; ++ri)
          Aout[(size_t)(row + ri) * 80 + col] = acc[m][nf][ri];
      }
    }
}

// ---------- norm_conv v2 (validated r27) ----------------------------------------------
__global__ __launch_bounds__(256) void norm_conv(
    const float* __restrict__ att, const float* __restrict__ den,
    const float* __restrict__ Wo,
    uint16_t* __restrict__ ath, uint16_t* __restrict__ atl,
    uint16_t* __restrict__ wfh) {
  const int bid = blockIdx.x;
  const int tid = threadIdx.x;
  if (bid < 4096) {
    const int m = bid;                      // att row b*2048+s
    const int hh = tid >> 5;                // head of cols [tid*8, tid*8+8)
    const float inv = 1.f / den[((size_t)(m >> 11) * 8 + hh) * SLEN + (m & 2047)];
    const size_t off = (size_t)m * 2048 + tid * 8;
    float4 a = *(const float4*)&att[off];
    float4 b = *(const float4*)&att[off + 4];
    a.x *= inv; a.y *= inv; a.z *= inv; a.w *= inv;
    b.x *= inv; b.y *= inv; b.z *= inv; b.w *= inv;
    short8 hi, lo;
    packsplit8(a, b, hi, lo);
    *(short8*)&ath[off] = hi;
    *(short8*)&atl[off] = lo;
  } else {
    const int g = (bid - 4096) * 256 + tid; // 0..524287
    const int lane_ = g & 63;
    const int cf = (g >> 6) & 7;
    const int kc = (g >> 9) & 63;
    const int ct2 = g >> 15;                // 0..15
    const int col = ct2 * 128 + cf * 16 + (lane_ & 15);
    const int kb = kc * 32 + 8 * (lane_ >> 4);
    float x[8];
    #pragma unroll
    for (int e = 0; e < 8; ++e) x[e] = Wo[(size_t)(kb + e) * 2048 + col];
    short8 hi;
    packhi8(make_float4(x[0], x[1], x[2], x[3]),
            make_float4(x[4], x[5], x[6], x[7]), hi);
    *(short8*)&wfh[(size_t)g * 8] = hi;
  }
}

// ---------- gemm_norm v6 (validated r28): BK=64 ---------------------------------------
__global__ __launch_bounds__(256) void gemm_norm(
    const uint16_t* __restrict__ ath, const uint16_t* __restrict__ atl,
    const uint16_t* __restrict__ wfh, float* __restrict__ C) {
  __shared__ uint16_t Ah[16 * 520], Al[16 * 520], Bh[16 * 520];
  const int tid = threadIdx.x;
  const int bid = blockIdx.x;          // 0..511
  const int work = (bid & 7) * 64 + (bid >> 3);
  const int ct2 = work & 15;
  const int col0 = ct2 * 128;
  const int row0 = (work >> 4) * 128;
  const int lane = tid & 63;
  const int wv = tid >> 6;
  const int wr = wv >> 1, wc = wv & 1;

  f32x4 acc[4][4];
  #pragma unroll
  for (int m = 0; m < 4; ++m)
    #pragma unroll
    for (int n = 0; n < 4; ++n) acc[m][n] = (f32x4){0.f, 0.f, 0.f, 0.f};

  const int ar = tid >> 1;
  const int akb = (tid & 1) * 16;
  const int ia0 = (ar >> 4) * 520 + (ar & 15) * 8 + (akb >> 3) * 128;
  const int bf_ = tid >> 5;
  const int boff = (tid & 31) * 16;
  const int ib = bf_ * 520 + boff;

  for (int kc2 = 0; kc2 < 32; ++kc2) {
    short8 a_h[2][2], a_l[2][2], b_h[2][2];
    #pragma unroll
    for (int c2 = 0; c2 < 2; ++c2) {
      const size_t aoff = (size_t)(row0 + ar) * 2048 + kc2 * 64 + c2 * 32 + akb;
      a_h[c2][0] = *(const short8*)&ath[aoff];
      a_h[c2][1] = *(const short8*)&ath[aoff + 8];
      a_l[c2][0] = *(const short8*)&atl[aoff];
      a_l[c2][1] = *(const short8*)&atl[aoff + 8];
      const size_t boffg = ((size_t)(ct2 * 64 + kc2 * 2 + c2) * 8 + bf_) * 512 + boff;
      b_h[c2][0] = *(const short8*)&wfh[boffg];
      b_h[c2][1] = *(const short8*)&wfh[boffg + 8];
    }
    __syncthreads();
    #pragma unroll
    for (int c2 = 0; c2 < 2; ++c2) {
      const int fa = c2 * 8 * 520;
      *(short8*)&Ah[fa + ia0] = a_h[c2][0];  *(short8*)&Ah[fa + ia0 + 128] = a_h[c2][1];
      *(short8*)&Al[fa + ia0] = a_l[c2][0];  *(short8*)&Al[fa + ia0 + 128] = a_l[c2][1];
      *(short8*)&Bh[fa + ib] = b_h[c2][0];   *(short8*)&Bh[fa + ib + 8] = b_h[c2][1];
    }
    __syncthreads();
    #pragma unroll
    for (int c2 = 0; c2 < 2; ++c2) {
      const int fb = c2 * 8;
      short8 bhf[4];
      #pragma unroll
      for (int nf = 0; nf < 4; ++nf)
        bhf[nf] = *(const short8*)&Bh[(fb + wc * 4 + nf) * 520 + lane * 8];
      #pragma unroll
      for (int m = 0; m < 4; ++m) {
        const short8 ahf = *(const short8*)&Ah[(fb + wr * 4 + m) * 520 + lane * 8];
        const short8 alf = *(const short8*)&Al[(fb + wr * 4 + m) * 520 + lane * 8];
        #pragma unroll
        for (int nf = 0; nf < 4; ++nf) {
          acc[m][nf] = __builtin_amdgcn_mfma_f32_16x16x32_bf16(ahf, bhf[nf], acc[m][nf], 0, 0, 0);
          acc[m][nf] = __builtin_amdgcn_mfma_f32_16x16x32_bf16(alf, bhf[nf], acc[m][nf], 0, 0, 0);
        }
      }
    }
  }
  #pragma unroll
  for (int m = 0; m < 4; ++m)
    #pragma unroll
    for (int nf = 0; nf < 4; ++nf) {
      const int row = row0 + wr * 64 + m * 16 + ((lane >> 4) << 2);
      const int col = col0 + wc * 64 + nf * 16 + (lane & 15);
      #pragma unroll
      for (int ri = 0; ri < 4; ++ri)
        C[(size_t)(row + ri) * HID + col] = acc[m][nf][ri];
    }
}

// ------------- RoPE + rank contraction v4 (validated r26, unchanged) ------------------
__global__ __launch_bounds__(256) void qkv_rope(
    const float* __restrict__ Aall,
    const float* __restrict__ Bq, const float* __restrict__ Bk,
    const float* __restrict__ Bv,
    const float* __restrict__ fc, const float* __restrict__ fs,
    uint16_t* __restrict__ qhg, uint16_t* __restrict__ qlg,
    uint16_t* __restrict__ khg, uint16_t* __restrict__ vvg) {
  const int m = blockIdx.x;        // 0..4095  (b*SLEN + s)
  const int s = m & (SLEN - 1);
  const int b = m >> 11;
  const int tid = threadIdx.x;
  __shared__ float Al[80];         // A_q[48] | A_k[16] | A_v[16]

  if (tid < 20) *(float4*)&Al[tid * 4] = *(const float4*)&Aall[(size_t)m * 80 + tid * 4];
  __syncthreads();

  const size_t tbase = (size_t)b * NH * SLEN * HD + (size_t)s * HD;
  if (tid < 128) {
    const int j = tid;
    const float cz = fc[s * 128 + j], sz = fs[s * 128 + j];
    float qe[8], qo[8];
    #pragma unroll
    for (int hh = 0; hh < 8; ++hh) { qe[hh] = 0.f; qo[hh] = 0.f; }
    #pragma unroll
    for (int r = 0; r < 6; ++r) {
      const float2 x = *(const float2*)&Bq[(size_t)m * 1536 + r * 256 + 2 * j];
      const float re = x.x * cz - x.y * sz;
      const float ro = x.x * sz + x.y * cz;
      #pragma unroll
      for (int hh = 0; hh < 8; ++hh) {
        const float a = Al[hh * 6 + r];
        qe[hh] = fmaf(a, re, qe[hh]);
        qo[hh] = fmaf(a, ro, qo[hh]);
      }
    }
    const float qs = SCALING / 6.f;
    #pragma unroll
    for (int hh = 0; hh < 8; ++hh) {
      const float x0 = qe[hh] * qs, x1 = qo[hh] * qs;
      const uint16_t h0 = bfhi(x0), h1 = bfhi(x1);
      const size_t eb = (tbase + (size_t)hh * SLEN * HD + 2 * j) >> 1;
      ((uint32_t*)qhg)[eb] = (uint32_t)h0 | ((uint32_t)h1 << 16);
      ((uint32_t*)qlg)[eb] = packbf2(x0 - bf2f(h0), x1 - bf2f(h1));
    }
  } else {
    const int j = tid - 128;
    const float cz = fc[s * 128 + j], sz = fs[s * 128 + j];
    float ke_[8], ko_[8], ve_[8], vo_[8];
    #pragma unroll
    for (int hh = 0; hh < 8; ++hh) { ke_[hh]=0.f; ko_[hh]=0.f; ve_[hh]=0.f; vo_[hh]=0.f; }
    #pragma unroll
    for (int r = 0; r < 2; ++r) {
      const float2 xk = *(const float2*)&Bk[(size_t)m * 512 + r * 256 + 2 * j];
      const float2 xv = *(const float2*)&Bv[(size_t)m * 512 + r * 256 + 2 * j];
      const float re = xk.x * cz - xk.y * sz;
      const float ro = xk.x * sz + xk.y * cz;
      #pragma unroll
      for (int hh = 0; hh < 8; ++hh) {
        const float ak = Al[48 + hh * 2 + r];
        const float av = Al[64 + hh * 2 + r];
        ke_[hh] = fmaf(ak, re, ke_[hh]);
        ko_[hh] = fmaf(ak, ro, ko_[hh]);
        ve_[hh] = fmaf(av, xv.x, ve_[hh]);
        vo_[hh] = fmaf(av, xv.y, vo_[hh]);
      }
    }
    #pragma unroll
    for (int hh = 0; hh < 8; ++hh) {
      const size_t eb = (tbase + (size_t)hh * SLEN * HD + 2 * j) >> 1;
      ((uint32_t*)khg)[eb] = packbf2(ke_[hh] * 0.5f, ko_[hh] * 0.5f);
      ((uint32_t*)vvg)[eb] = packbf2(ve_[hh] * 0.5f, vo_[hh] * 0.5f);
    }
  }
}

// ------------- zero att + den (harness poisons ws; atomics need zeros) ----------------
__global__ __launch_bounds__(256) void zero_acc(float* __restrict__ att,
                                                float* __restrict__ den) {
  const int idx = blockIdx.x * 256 + threadIdx.x;   // float4 index
  const float4 z = {0.f, 0.f, 0.f, 0.f};
  *(float4*)&att[(size_t)idx * 4] = z;              // grid covers 8,388,608 floats
  if (idx < 8192) *(float4*)&den[(size_t)idx * 4] = z;   // 32768 floats
}

// ------------- causal softcapped attention v10: 1 q-tile per block, 1024 blocks -------
// vs v9: fold split — block = (bh, qt, hf) instead of (bh, pair, hf). Grid 512 -> 1024;
// occupancy cap moves from grid (2 blocks/CU) to LDS (3 blocks/CU). Per-q-row math,
// k-order, and 2-addends-per-address atomic merge unchanged -> bit-exact+deterministic.
// LPT via qt = 31 - (bid>>5).
#define KLD 264
#define VLD 40
#define PLD 40
__global__ __launch_bounds__(256, 2) void attn_mfma(
    const uint16_t* __restrict__ qhg, const uint16_t* __restrict__ qlg,
    const uint16_t* __restrict__ khg, const uint16_t* __restrict__ vvg,
    float* __restrict__ att, float* __restrict__ den_g) {
  __shared__ uint16_t Khs[32 * KLD];   // 16896 B
  __shared__ uint16_t Vts[256 * VLD];  // 20480 B
  __shared__ uint16_t Ps[4 * 16 * PLD];//  5120 B   (total 42496 B -> 3 blocks/CU)
  const int tid = threadIdx.x;
  const int lane = tid & 63;
  const int w = tid >> 6;
  const int l15 = lane & 15;
  const int l4 = lane >> 4;
  const int bid = blockIdx.x;          // 0..1023
  const int bh = bid & 15;             // low bits -> per-bh K/V pins to one XCD L2
  const int hf = (bid >> 4) & 1;       // k-parity half
  const int qt = 31 - (bid >> 5);      // heavy q-tiles dispatched first (LPT)
  const int b = bh >> 3, h = bh & 7;
  const size_t base = (size_t)bh * SLEN * HD;
  const uint16_t* khb = &khg[base];
  const uint16_t* vvb = &vvg[base];
  const int sr = tid & 31;
  const int sc = (tid >> 5) * 32;

  const int q0 = qt * 64;
  short8 qh[8], ql[8];
  {
    const uint16_t* qhp = &qhg[base + (size_t)(q0 + w * 16 + l15) * HD + 8 * l4];
    const uint16_t* qlp = &qlg[base + (size_t)(q0 + w * 16 + l15) * HD + 8 * l4];
    #pragma unroll
    for (int f = 0; f < 8; ++f) {
      qh[f] = *(const short8*)&qhp[32 * f];
      ql[f] = *(const short8*)&qlp[32 * f];
    }
  }
  f32x4 acc[16];
  #pragma unroll
  for (int df = 0; df < 16; ++df) acc[df] = (f32x4){0.f, 0.f, 0.f, 0.f};
  float den[4] = {0.f, 0.f, 0.f, 0.f};

  const int myrow = q0 + w * 16 + l4 * 4;
  const int rowmax = q0 + w * 16 + 15;
  const int nkt = 2 * qt + 2;

  short8 kh8[4], vv8[4];
  {
    const uint16_t* kp = &khb[(size_t)(hf * 32 + sr) * HD + sc];
    const uint16_t* vp = &vvb[(size_t)(hf * 32 + sr) * HD + sc];
    #pragma unroll
    for (int j = 0; j < 4; ++j) {
      kh8[j] = *(const short8*)&kp[8 * j];
      vv8[j] = *(const short8*)&vp[8 * j];
    }
  }

  for (int kt = hf; kt < nkt; kt += 2) {
    const int k0 = kt * 32;
    #pragma unroll
    for (int j = 0; j < 4; ++j)
      *(short8*)&Khs[sr * KLD + sc + 8 * j] = kh8[j];
    #pragma unroll
    for (int j = 0; j < 4; ++j) {
      const short8 s8 = vv8[j];
      #pragma unroll
      for (int i = 0; i < 8; ++i)
        Vts[(sc + 8 * j + i) * VLD + sr] = (uint16_t)s8[i];
    }
    if (kt + 2 < nkt) {
      const uint16_t* kp = &khb[(size_t)(k0 + 64 + sr) * HD + sc];
      const uint16_t* vp = &vvb[(size_t)(k0 + 64 + sr) * HD + sc];
      #pragma unroll
      for (int j = 0; j < 4; ++j) {
        kh8[j] = *(const short8*)&kp[8 * j];
        vv8[j] = *(const short8*)&vp[8 * j];
      }
    }
    asm volatile("s_waitcnt lgkmcnt(0)" ::: "memory");
    __builtin_amdgcn_sched_barrier(0);
    __builtin_amdgcn_s_barrier();
    __builtin_amdgcn_sched_barrier(0);
    if (k0 <= rowmax) {
      f32x4 sfr[2];
      __builtin_amdgcn_s_setprio(1);
      #pragma unroll
      for (int kf = 0; kf < 2; ++kf) {
        f32x4 c0 = (f32x4){0.f, 0.f, 0.f, 0.f};
        f32x4 c1 = c0;
        #pragma unroll
        for (int dc = 0; dc < 8; ++dc) {
          const short8 kh = *(const short8*)&Khs[(16 * kf + l15) * KLD + 32 * dc + 8 * l4];
          c0 = __builtin_amdgcn_mfma_f32_16x16x32_bf16(qh[dc], kh, c0, 0, 0, 0);
          c1 = __builtin_amdgcn_mfma_f32_16x16x32_bf16(ql[dc], kh, c1, 0, 0, 0);
        }
        sfr[kf] = c0 + c1;
      }
      __builtin_amdgcn_s_setprio(0);
      uint16_t* pw = &Ps[w * 16 * PLD];
      #pragma unroll
      for (int kf = 0; kf < 2; ++kf) {
        #pragma unroll
        for (int ri = 0; ri < 4; ++ri) {
          const float pd = sfr[kf][ri];
          const float t1 = exp2f(pd * 0.0577078016f);
          float e = exp2f(-144.26950409f * __builtin_amdgcn_rcpf(t1 + 1.f));
          if (k0 + 16 * kf + l15 > myrow + ri) e = 0.f;
          den[ri] += e;
          pw[(l4 * 4 + ri) * PLD + 16 * kf + l15] = bfhi(e);
        }
      }
      const short8 pa = *(const short8*)&pw[l15 * PLD + 8 * l4];
      __builtin_amdgcn_s_setprio(1);
      #pragma unroll
      for (int df = 0; df < 16; ++df) {
        const short8 vb = *(const short8*)&Vts[(16 * df + l15) * VLD + 8 * l4];
        acc[df] = __builtin_amdgcn_mfma_f32_16x16x32_bf16(pa, vb, acc[df], 0, 0, 0);
      }
      __builtin_amdgcn_s_setprio(0);
    }
    __builtin_amdgcn_sched_barrier(0);
    __builtin_amdgcn_s_barrier();
    __builtin_amdgcn_sched_barrier(0);
  }
  #pragma unroll
  for (int ri = 0; ri < 4; ++ri) {
    den[ri] += __shfl_xor(den[ri], 1);
    den[ri] += __shfl_xor(den[ri], 2);
    den[ri] += __shfl_xor(den[ri], 4);
    den[ri] += __shfl_xor(den[ri], 8);
  }
  if (l15 == 0) {
    #pragma unroll
    for (int ri = 0; ri < 4; ++ri)
      atomAddF(&den_g[(size_t)bh * SLEN + myrow + ri], den[ri]);
  }
  float* op = &att[((size_t)(b * SLEN + myrow)) * (NH * HD) + h * HD + l15];
  #pragma unroll
  for (int ri = 0; ri < 4; ++ri)
    #pragma unroll
    for (int df = 0; df < 16; ++df)
      atomAddF(&op[(size_t)ri * (NH * HD) + 16 * df], acc[df][ri]);
}

extern "C" void kernel_launch(void* const* d_in, const int* in_sizes, int n_in,
                              void* d_out, int out_size, void* d_ws, size_t ws_size,
                              hipStream_t stream) {
  const float* hs  = (const float*)d_in[0];
  const float* fc  = (const float*)d_in[1];
  const float* fs  = (const float*)d_in[2];
  // d_in[3] = mask: pure causal, handled analytically.
  const float* WAq = (const float*)d_in[4];
  const float* WAk = (const float*)d_in[5];
  const float* WAv = (const float*)d_in[6];
  const float* WBq = (const float*)d_in[7];
  const float* WBk = (const float*)d_in[8];
  const float* WBv = (const float*)d_in[9];
  const float* Wo  = (const float*)d_in[10];
  float* out = (float*)d_out;

  // Workspace (floats), peak 127 MB. Same validated lifetime map as r22/r26/r27.
  float* ws   = (float*)d_ws;
  float* Bq   = ws;
  float* Bk   = Bq + (size_t)MTOT * 1536;
  float* Bv   = Bk + (size_t)MTOT * 512;
  uint16_t* qh = (uint16_t*)(Bv + (size_t)MTOT * 512);
  uint16_t* ql = qh + (size_t)8388608;
  uint16_t* kh = ql + (size_t)8388608;
  uint16_t* vv = kh + (size_t)16777216;   // skip the unused kl slot
  float* Aall = ws + (size_t)31457280;
  float* att  = ws;
  float* den  = Bv;
  uint16_t* hsh  = (uint16_t*)(ws + (size_t)10485760);
  uint16_t* hsl  = hsh + (size_t)8388608;
  uint16_t* wfh  = (uint16_t*)(ws + (size_t)18874368);
  uint16_t* atth = (uint16_t*)(ws + (size_t)10485760);
  uint16_t* attl = atth + (size_t)8388608;
  uint16_t* wofh = (uint16_t*)(ws + (size_t)18874368);

  conv_pre<<<dim3(4096 + 2688), 256, 0, stream>>>(hs, WBq, WBk, WBv, WAq, WAk, WAv,
                                                  hsh, hsl, wfh);
  gemm_proj<<<dim3(672), 256, 0, stream>>>(hsh, hsl, wfh, Bq, Bk, Bv, Aall);
  qkv_rope<<<MTOT, 256, 0, stream>>>(Aall, Bq, Bk, Bv, fc, fs, qh, ql, kh, vv);
  zero_acc<<<8192, 256, 0, stream>>>(att, den);
  attn_mfma<<<dim3(1024), 256, 0, stream>>>(qh, ql, kh, vv, att, den);
  norm_conv<<<dim3(4096 + 2048), 256, 0, stream>>>(att, den, Wo, atth, attl, wofh);
  gemm_norm<<<dim3(512), 256, 0, stream>>>(atth, attl, wofh, out);
}

// Round 30
// 342.246 us; speedup vs baseline: 1.0188x; 1.0188x over previous
//
#include <hip/hip_runtime.h>
#include <cstdint>

#define HID 2048
#define SLEN 2048
#define NH 8
#define HD 256
#define MTOT 4096

constexpr float SCALING = 0.0625f;   // 256^-0.5
constexpr float SOFTCAP = 50.0f;

typedef __attribute__((ext_vector_type(8))) short short8;
typedef __attribute__((ext_vector_type(4))) float f32x4;

__device__ __forceinline__ uint16_t bfhi(float x) {
  return (uint16_t)(__float_as_uint(x) >> 16);           // truncate
}
__device__ __forceinline__ float bf2f(uint16_t h) {
  return __uint_as_float((uint32_t)h << 16);
}
__device__ __forceinline__ void packsplit8(const float4 a, const float4 b,
                                           short8& hi, short8& lo) {
  const float x[8] = {a.x, a.y, a.z, a.w, b.x, b.y, b.z, b.w};
  #pragma unroll
  for (int i = 0; i < 8; ++i) {
    const uint32_t u = __float_as_uint(x[i]);
    const uint16_t h = (uint16_t)(u >> 16);
    const float r = x[i] - bf2f(h);
    hi[i] = (short)h;
    lo[i] = (short)(__float_as_uint(r) >> 16);
  }
}
__device__ __forceinline__ void packhi8(const float4 a, const float4 b, short8& hi) {
  hi[0] = (short)bfhi(a.x); hi[1] = (short)bfhi(a.y);
  hi[2] = (short)bfhi(a.z); hi[3] = (short)bfhi(a.w);
  hi[4] = (short)bfhi(b.x); hi[5] = (short)bfhi(b.y);
  hi[6] = (short)bfhi(b.z); hi[7] = (short)bfhi(b.w);
}
__device__ __forceinline__ void atomAddF(float* p, float v) {
  __hip_atomic_fetch_add(p, v, __ATOMIC_RELAXED, __HIP_MEMORY_SCOPE_AGENT);
}
__device__ __forceinline__ uint32_t packbf2(float x0, float x1) {
  return (uint32_t)bfhi(x0) | ((uint32_t)bfhi(x1) << 16);
}

// ---------- conv_pre v2 (validated r27): hs -> split; weights -> bf16 frag-native -----
__global__ __launch_bounds__(256) void conv_pre(
    const float* __restrict__ hs,
    const float* __restrict__ WBq, const float* __restrict__ WBk,
    const float* __restrict__ WBv,
    const float* __restrict__ WAq, const float* __restrict__ WAk,
    const float* __restrict__ WAv,
    uint16_t* __restrict__ hsh, uint16_t* __restrict__ hsl,
    uint16_t* __restrict__ wfh) {
  const int bid = blockIdx.x;
  const int tid = threadIdx.x;
  if (bid < 4096) {
    const size_t off = (size_t)bid * 2048 + tid * 8;
    const float4 a = *(const float4*)&hs[off];
    const float4 b = *(const float4*)&hs[off + 4];
    short8 hi, lo;
    packsplit8(a, b, hi, lo);
    *(short8*)&hsh[off] = hi;
    *(short8*)&hsl[off] = lo;
  } else {
    const int g = (bid - 4096) * 256 + tid;   // 0..688127
    const int lane_ = g & 63;
    const int cf = (g >> 6) & 7;
    const int kc = (g >> 9) & 63;
    const int ct = g >> 15;                   // 0..20
    const int col = cf * 16 + (lane_ & 15);
    const int kb = kc * 32 + 8 * (lane_ >> 4);
    float x[8];
    #pragma unroll
    for (int e = 0; e < 8; ++e) {
      const int k = kb + e;
      float v;
      if (ct == 12) {
        if (col < 48)      v = WAq[(size_t)k * 48 + col];
        else if (col < 64) v = WAk[(size_t)k * 16 + (col - 48)];
        else if (col < 80) v = WAv[(size_t)k * 16 + (col - 64)];
        else               v = 0.f;
      } else if (ct < 12) {
        v = WBq[(size_t)k * 1536 + ct * 128 + col];
      } else if (ct < 17) {
        v = WBk[(size_t)k * 512 + (ct - 13) * 128 + col];
      } else {
        v = WBv[(size_t)k * 512 + (ct - 17) * 128 + col];
      }
      x[e] = v;
    }
    short8 hi;
    packhi8(make_float4(x[0], x[1], x[2], x[3]),
            make_float4(x[4], x[5], x[6], x[7]), hi);
    *(short8*)&wfh[(size_t)g * 8] = hi;
  }
}

// ---------- gemm_proj v6 (validated r28): BK=64, 2-term split -------------------------
__global__ __launch_bounds__(256) void gemm_proj(
    const uint16_t* __restrict__ hsh, const uint16_t* __restrict__ hsl,
    const uint16_t* __restrict__ wfh,
    float* __restrict__ Cq, float* __restrict__ Ck, float* __restrict__ Cv,
    float* __restrict__ Aout) {
  __shared__ uint16_t Ah[16 * 520], Al[16 * 520], Bh[16 * 520];
  const int tid = threadIdx.x;
  const int bid = blockIdx.x;          // 0..671
  const int work = (bid & 7) * 84 + (bid >> 3);
  const int ct = work % 21;
  const int row0 = (work / 21) * 128;
  const bool special = (ct == 12);
  float* Cmat = Cq; int Nseg = 1536; int col0 = ct * 128;
  if (ct >= 17)      { Cmat = Cv; Nseg = 512; col0 = (ct - 17) * 128; }
  else if (ct >= 13) { Cmat = Ck; Nseg = 512; col0 = (ct - 13) * 128; }
  const int lane = tid & 63;
  const int wv = tid >> 6;
  const int wr = wv >> 1, wc = wv & 1;

  f32x4 acc[4][4];
  #pragma unroll
  for (int m = 0; m < 4; ++m)
    #pragma unroll
    for (int n = 0; n < 4; ++n) acc[m][n] = (f32x4){0.f, 0.f, 0.f, 0.f};

  const int ar = tid >> 1;             // A row 0..127
  const int akb = (tid & 1) * 16;      // k half within chunk
  const int ia0 = (ar >> 4) * 520 + (ar & 15) * 8 + (akb >> 3) * 128;
  const int bf_ = tid >> 5;            // B copy frag 0..7
  const int boff = (tid & 31) * 16;    // 0..496
  const int ib = bf_ * 520 + boff;

  for (int kc2 = 0; kc2 < 32; ++kc2) {
    short8 a_h[2][2], a_l[2][2], b_h[2][2];
    #pragma unroll
    for (int c2 = 0; c2 < 2; ++c2) {
      const size_t aoff = (size_t)(row0 + ar) * 2048 + kc2 * 64 + c2 * 32 + akb;
      a_h[c2][0] = *(const short8*)&hsh[aoff];
      a_h[c2][1] = *(const short8*)&hsh[aoff + 8];
      a_l[c2][0] = *(const short8*)&hsl[aoff];
      a_l[c2][1] = *(const short8*)&hsl[aoff + 8];
      const size_t boffg = ((size_t)(ct * 64 + kc2 * 2 + c2) * 8 + bf_) * 512 + boff;
      b_h[c2][0] = *(const short8*)&wfh[boffg];
      b_h[c2][1] = *(const short8*)&wfh[boffg + 8];
    }
    __syncthreads();   // previous tile fully consumed
    #pragma unroll
    for (int c2 = 0; c2 < 2; ++c2) {
      const int fa = c2 * 8 * 520;
      *(short8*)&Ah[fa + ia0] = a_h[c2][0];  *(short8*)&Ah[fa + ia0 + 128] = a_h[c2][1];
      *(short8*)&Al[fa + ia0] = a_l[c2][0];  *(short8*)&Al[fa + ia0 + 128] = a_l[c2][1];
      *(short8*)&Bh[fa + ib] = b_h[c2][0];   *(short8*)&Bh[fa + ib + 8] = b_h[c2][1];
    }
    __syncthreads();
    #pragma unroll
    for (int c2 = 0; c2 < 2; ++c2) {
      const int fb = c2 * 8;
      short8 bhf[4];
      #pragma unroll
      for (int nf = 0; nf < 4; ++nf)
        bhf[nf] = *(const short8*)&Bh[(fb + wc * 4 + nf) * 520 + lane * 8];
      #pragma unroll
      for (int m = 0; m < 4; ++m) {
        const short8 ahf = *(const short8*)&Ah[(fb + wr * 4 + m) * 520 + lane * 8];
        const short8 alf = *(const short8*)&Al[(fb + wr * 4 + m) * 520 + lane * 8];
        #pragma unroll
        for (int nf = 0; nf < 4; ++nf) {
          acc[m][nf] = __builtin_amdgcn_mfma_f32_16x16x32_bf16(ahf, bhf[nf], acc[m][nf], 0, 0, 0);
          acc[m][nf] = __builtin_amdgcn_mfma_f32_16x16x32_bf16(alf, bhf[nf], acc[m][nf], 0, 0, 0);
        }
      }
    }
  }
  #pragma unroll
  for (int m = 0; m < 4; ++m)
    #pragma unroll
    for (int nf = 0; nf < 4; ++nf) {
      const int row = row0 + wr * 64 + m * 16 + ((lane >> 4) << 2);
      const int col = wc * 64 + nf * 16 + (lane & 15);
      if (!special) {
        #pragma unroll
        for (int ri = 0; ri < 4; ++ri)
          Cmat[(size_t)(row + ri) * Nseg + col0 + col] = acc[m][nf][ri];
      } else if (col < 80) {
        #pragma unroll
        for (int ri = 0; ri < 4; ++ri)
          Aout[(size_t)(row + ri) * 80 + col] = acc[m][nf][ri];
      }
    }
}

// ---------- norm_conv v2 (validated r27) ----------------------------------------------
__global__ __launch_bounds__(256) void norm_conv(
    const float* __restrict__ att, const float* __restrict__ den,
    const float* __restrict__ Wo,
    uint16_t* __restrict__ ath, uint16_t* __restrict__ atl,
    uint16_t* __restrict__ wfh) {
  const int bid = blockIdx.x;
  const int tid = threadIdx.x;
  if (bid < 4096) {
    const int m = bid;                      // att row b*2048+s
    const int hh = tid >> 5;                // head of cols [tid*8, tid*8+8)
    const float inv = 1.f / den[((size_t)(m >> 11) * 8 + hh) * SLEN + (m & 2047)];
    const size_t off = (size_t)m * 2048 + tid * 8;
    float4 a = *(const float4*)&att[off];
    float4 b = *(const float4*)&att[off + 4];
    a.x *= inv; a.y *= inv; a.z *= inv; a.w *= inv;
    b.x *= inv; b.y *= inv; b.z *= inv; b.w *= inv;
    short8 hi, lo;
    packsplit8(a, b, hi, lo);
    *(short8*)&ath[off] = hi;
    *(short8*)&atl[off] = lo;
  } else {
    const int g = (bid - 4096) * 256 + tid; // 0..524287
    const int lane_ = g & 63;
    const int cf = (g >> 6) & 7;
    const int kc = (g >> 9) & 63;
    const int ct2 = g >> 15;                // 0..15
    const int col = ct2 * 128 + cf * 16 + (lane_ & 15);
    const int kb = kc * 32 + 8 * (lane_ >> 4);
    float x[8];
    #pragma unroll
    for (int e = 0; e < 8; ++e) x[e] = Wo[(size_t)(kb + e) * 2048 + col];
    short8 hi;
    packhi8(make_float4(x[0], x[1], x[2], x[3]),
            make_float4(x[4], x[5], x[6], x[7]), hi);
    *(short8*)&wfh[(size_t)g * 8] = hi;
  }
}

// ---------- gemm_norm v6 (validated r28): BK=64 ---------------------------------------
__global__ __launch_bounds__(256) void gemm_norm(
    const uint16_t* __restrict__ ath, const uint16_t* __restrict__ atl,
    const uint16_t* __restrict__ wfh, float* __restrict__ C) {
  __shared__ uint16_t Ah[16 * 520], Al[16 * 520], Bh[16 * 520];
  const int tid = threadIdx.x;
  const int bid = blockIdx.x;          // 0..511
  const int work = (bid & 7) * 64 + (bid >> 3);
  const int ct2 = work & 15;
  const int col0 = ct2 * 128;
  const int row0 = (work >> 4) * 128;
  const int lane = tid & 63;
  const int wv = tid >> 6;
  const int wr = wv >> 1, wc = wv & 1;

  f32x4 acc[4][4];
  #pragma unroll
  for (int m = 0; m < 4; ++m)
    #pragma unroll
    for (int n = 0; n < 4; ++n) acc[m][n] = (f32x4){0.f, 0.f, 0.f, 0.f};

  const int ar = tid >> 1;
  const int akb = (tid & 1) * 16;
  const int ia0 = (ar >> 4) * 520 + (ar & 15) * 8 + (akb >> 3) * 128;
  const int bf_ = tid >> 5;
  const int boff = (tid & 31) * 16;
  const int ib = bf_ * 520 + boff;

  for (int kc2 = 0; kc2 < 32; ++kc2) {
    short8 a_h[2][2], a_l[2][2], b_h[2][2];
    #pragma unroll
    for (int c2 = 0; c2 < 2; ++c2) {
      const size_t aoff = (size_t)(row0 + ar) * 2048 + kc2 * 64 + c2 * 32 + akb;
      a_h[c2][0] = *(const short8*)&ath[aoff];
      a_h[c2][1] = *(const short8*)&ath[aoff + 8];
      a_l[c2][0] = *(const short8*)&atl[aoff];
      a_l[c2][1] = *(const short8*)&atl[aoff + 8];
      const size_t boffg = ((size_t)(ct2 * 64 + kc2 * 2 + c2) * 8 + bf_) * 512 + boff;
      b_h[c2][0] = *(const short8*)&wfh[boffg];
      b_h[c2][1] = *(const short8*)&wfh[boffg + 8];
    }
    __syncthreads();
    #pragma unroll
    for (int c2 = 0; c2 < 2; ++c2) {
      const int fa = c2 * 8 * 520;
      *(short8*)&Ah[fa + ia0] = a_h[c2][0];  *(short8*)&Ah[fa + ia0 + 128] = a_h[c2][1];
      *(short8*)&Al[fa + ia0] = a_l[c2][0];  *(short8*)&Al[fa + ia0 + 128] = a_l[c2][1];
      *(short8*)&Bh[fa + ib] = b_h[c2][0];   *(short8*)&Bh[fa + ib + 8] = b_h[c2][1];
    }
    __syncthreads();
    #pragma unroll
    for (int c2 = 0; c2 < 2; ++c2) {
      const int fb = c2 * 8;
      short8 bhf[4];
      #pragma unroll
      for (int nf = 0; nf < 4; ++nf)
        bhf[nf] = *(const short8*)&Bh[(fb + wc * 4 + nf) * 520 + lane * 8];
      #pragma unroll
      for (int m = 0; m < 4; ++m) {
        const short8 ahf = *(const short8*)&Ah[(fb + wr * 4 + m) * 520 + lane * 8];
        const short8 alf = *(const short8*)&Al[(fb + wr * 4 + m) * 520 + lane * 8];
        #pragma unroll
        for (int nf = 0; nf < 4; ++nf) {
          acc[m][nf] = __builtin_amdgcn_mfma_f32_16x16x32_bf16(ahf, bhf[nf], acc[m][nf], 0, 0, 0);
          acc[m][nf] = __builtin_amdgcn_mfma_f32_16x16x32_bf16(alf, bhf[nf], acc[m][nf], 0, 0, 0);
        }
      }
    }
  }
  #pragma unroll
  for (int m = 0; m < 4; ++m)
    #pragma unroll
    for (int nf = 0; nf < 4; ++nf) {
      const int row = row0 + wr * 64 + m * 16 + ((lane >> 4) << 2);
      const int col = col0 + wc * 64 + nf * 16 + (lane & 15);
      #pragma unroll
      for (int ri = 0; ri < 4; ++ri)
        C[(size_t)(row + ri) * HID + col] = acc[m][nf][ri];
    }
}

// ------------- RoPE + rank contraction v4 (validated r26, unchanged) ------------------
__global__ __launch_bounds__(256) void qkv_rope(
    const float* __restrict__ Aall,
    const float* __restrict__ Bq, const float* __restrict__ Bk,
    const float* __restrict__ Bv,
    const float* __restrict__ fc, const float* __restrict__ fs,
    uint16_t* __restrict__ qhg, uint16_t* __restrict__ qlg,
    uint16_t* __restrict__ khg, uint16_t* __restrict__ vvg) {
  const int m = blockIdx.x;        // 0..4095  (b*SLEN + s)
  const int s = m & (SLEN - 1);
  const int b = m >> 11;
  const int tid = threadIdx.x;
  __shared__ float Al[80];         // A_q[48] | A_k[16] | A_v[16]

  if (tid < 20) *(float4*)&Al[tid * 4] = *(const float4*)&Aall[(size_t)m * 80 + tid * 4];
  __syncthreads();

  const size_t tbase = (size_t)b * NH * SLEN * HD + (size_t)s * HD;
  if (tid < 128) {
    const int j = tid;
    const float cz = fc[s * 128 + j], sz = fs[s * 128 + j];
    float qe[8], qo[8];
    #pragma unroll
    for (int hh = 0; hh < 8; ++hh) { qe[hh] = 0.f; qo[hh] = 0.f; }
    #pragma unroll
    for (int r = 0; r < 6; ++r) {
      const float2 x = *(const float2*)&Bq[(size_t)m * 1536 + r * 256 + 2 * j];
      const float re = x.x * cz - x.y * sz;
      const float ro = x.x * sz + x.y * cz;
      #pragma unroll
      for (int hh = 0; hh < 8; ++hh) {
        const float a = Al[hh * 6 + r];
        qe[hh] = fmaf(a, re, qe[hh]);
        qo[hh] = fmaf(a, ro, qo[hh]);
      }
    }
    const float qs = SCALING / 6.f;
    #pragma unroll
    for (int hh = 0; hh < 8; ++hh) {
      const float x0 = qe[hh] * qs, x1 = qo[hh] * qs;
      const uint16_t h0 = bfhi(x0), h1 = bfhi(x1);
      const size_t eb = (tbase + (size_t)hh * SLEN * HD + 2 * j) >> 1;
      ((uint32_t*)qhg)[eb] = (uint32_t)h0 | ((uint32_t)h1 << 16);
      ((uint32_t*)qlg)[eb] = packbf2(x0 - bf2f(h0), x1 - bf2f(h1));
    }
  } else {
    const int j = tid - 128;
    const float cz = fc[s * 128 + j], sz = fs[s * 128 + j];
    float ke_[8], ko_[8], ve_[8], vo_[8];
    #pragma unroll
    for (int hh = 0; hh < 8; ++hh) { ke_[hh]=0.f; ko_[hh]=0.f; ve_[hh]=0.f; vo_[hh]=0.f; }
    #pragma unroll
    for (int r = 0; r < 2; ++r) {
      const float2 xk = *(const float2*)&Bk[(size_t)m * 512 + r * 256 + 2 * j];
      const float2 xv = *(const float2*)&Bv[(size_t)m * 512 + r * 256 + 2 * j];
      const float re = xk.x * cz - xk.y * sz;
      const float ro = xk.x * sz + xk.y * cz;
      #pragma unroll
      for (int hh = 0; hh < 8; ++hh) {
        const float ak = Al[48 + hh * 2 + r];
        const float av = Al[64 + hh * 2 + r];
        ke_[hh] = fmaf(ak, re, ke_[hh]);
        ko_[hh] = fmaf(ak, ro, ko_[hh]);
        ve_[hh] = fmaf(av, xv.x, ve_[hh]);
        vo_[hh] = fmaf(av, xv.y, vo_[hh]);
      }
    }
    #pragma unroll
    for (int hh = 0; hh < 8; ++hh) {
      const size_t eb = (tbase + (size_t)hh * SLEN * HD + 2 * j) >> 1;
      ((uint32_t*)khg)[eb] = packbf2(ke_[hh] * 0.5f, ko_[hh] * 0.5f);
      ((uint32_t*)vvg)[eb] = packbf2(ve_[hh] * 0.5f, vo_[hh] * 0.5f);
    }
  }
}

// ------------- zero att + den (harness poisons ws; atomics need zeros) ----------------
__global__ __launch_bounds__(256) void zero_acc(float* __restrict__ att,
                                                float* __restrict__ den) {
  const int idx = blockIdx.x * 256 + threadIdx.x;   // float4 index
  const float4 z = {0.f, 0.f, 0.f, 0.f};
  *(float4*)&att[(size_t)idx * 4] = z;              // grid covers 8,388,608 floats
  if (idx < 8192) *(float4*)&den[(size_t)idx * 4] = z;   // 32768 floats
}

// ------------- causal softcapped attention v9 (validated r26/r28): paired fold --------
// Block (bh, p, hf): q-tiles 31-p then p, k-tiles kt ≡ hf (mod 2) -> every block does
// exactly 33 k-iters (perfect balance; r29 lesson: splitting the pair regresses).
// K plain bf16, 2-term QK; 2-addends-per-address atomic merge -> deterministic.
#define KLD 264
#define VLD 40
#define PLD 40
__global__ __launch_bounds__(256, 2) void attn_mfma(
    const uint16_t* __restrict__ qhg, const uint16_t* __restrict__ qlg,
    const uint16_t* __restrict__ khg, const uint16_t* __restrict__ vvg,
    float* __restrict__ att, float* __restrict__ den_g) {
  __shared__ uint16_t Khs[32 * KLD];   // 16896 B
  __shared__ uint16_t Vts[256 * VLD];  // 20480 B
  __shared__ uint16_t Ps[4 * 16 * PLD];//  5120 B   (total 42496 B)
  const int tid = threadIdx.x;
  const int lane = tid & 63;
  const int w = tid >> 6;
  const int l15 = lane & 15;
  const int l4 = lane >> 4;
  const int bid = blockIdx.x;
  const int bh = bid & 15;
  const int p = (bid >> 4) & 15;
  const int hf = bid >> 8;
  const int b = bh >> 3, h = bh & 7;
  const size_t base = (size_t)bh * SLEN * HD;
  const uint16_t* khb = &khg[base];
  const uint16_t* vvb = &vvg[base];
  const int sr = tid & 31;
  const int sc = (tid >> 5) * 32;

  #pragma unroll
  for (int sub = 0; sub < 2; ++sub) {
    const int qt = (sub == 0) ? (31 - p) : p;
    const int q0 = qt * 64;
    short8 qh[8], ql[8];
    {
      const uint16_t* qhp = &qhg[base + (size_t)(q0 + w * 16 + l15) * HD + 8 * l4];
      const uint16_t* qlp = &qlg[base + (size_t)(q0 + w * 16 + l15) * HD + 8 * l4];
      #pragma unroll
      for (int f = 0; f < 8; ++f) {
        qh[f] = *(const short8*)&qhp[32 * f];
        ql[f] = *(const short8*)&qlp[32 * f];
      }
    }
    f32x4 acc[16];
    #pragma unroll
    for (int df = 0; df < 16; ++df) acc[df] = (f32x4){0.f, 0.f, 0.f, 0.f};
    float den[4] = {0.f, 0.f, 0.f, 0.f};

    const int myrow = q0 + w * 16 + l4 * 4;
    const int rowmax = q0 + w * 16 + 15;
    const int nkt = 2 * qt + 2;

    short8 kh8[4], vv8[4];
    {
      const uint16_t* kp = &khb[(size_t)(hf * 32 + sr) * HD + sc];
      const uint16_t* vp = &vvb[(size_t)(hf * 32 + sr) * HD + sc];
      #pragma unroll
      for (int j = 0; j < 4; ++j) {
        kh8[j] = *(const short8*)&kp[8 * j];
        vv8[j] = *(const short8*)&vp[8 * j];
      }
    }

    for (int kt = hf; kt < nkt; kt += 2) {
      const int k0 = kt * 32;
      #pragma unroll
      for (int j = 0; j < 4; ++j)
        *(short8*)&Khs[sr * KLD + sc + 8 * j] = kh8[j];
      #pragma unroll
      for (int j = 0; j < 4; ++j) {
        const short8 s8 = vv8[j];
        #pragma unroll
        for (int i = 0; i < 8; ++i)
          Vts[(sc + 8 * j + i) * VLD + sr] = (uint16_t)s8[i];
      }
      if (kt + 2 < nkt) {
        const uint16_t* kp = &khb[(size_t)(k0 + 64 + sr) * HD + sc];
        const uint16_t* vp = &vvb[(size_t)(k0 + 64 + sr) * HD + sc];
        #pragma unroll
        for (int j = 0; j < 4; ++j) {
          kh8[j] = *(const short8*)&kp[8 * j];
          vv8[j] = *(const short8*)&vp[8 * j];
        }
      }
      asm volatile("s_waitcnt lgkmcnt(0)" ::: "memory");
      __builtin_amdgcn_sched_barrier(0);
      __builtin_amdgcn_s_barrier();
      __builtin_amdgcn_sched_barrier(0);
      if (k0 <= rowmax) {
        f32x4 sfr[2];
        __builtin_amdgcn_s_setprio(1);
        #pragma unroll
        for (int kf = 0; kf < 2; ++kf) {
          f32x4 c0 = (f32x4){0.f, 0.f, 0.f, 0.f};
          f32x4 c1 = c0;
          #pragma unroll
          for (int dc = 0; dc < 8; ++dc) {
            const short8 kh = *(const short8*)&Khs[(16 * kf + l15) * KLD + 32 * dc + 8 * l4];
            c0 = __builtin_amdgcn_mfma_f32_16x16x32_bf16(qh[dc], kh, c0, 0, 0, 0);
            c1 = __builtin_amdgcn_mfma_f32_16x16x32_bf16(ql[dc], kh, c1, 0, 0, 0);
          }
          sfr[kf] = c0 + c1;
        }
        __builtin_amdgcn_s_setprio(0);
        uint16_t* pw = &Ps[w * 16 * PLD];
        #pragma unroll
        for (int kf = 0; kf < 2; ++kf) {
          #pragma unroll
          for (int ri = 0; ri < 4; ++ri) {
            const float pd = sfr[kf][ri];
            const float t1 = exp2f(pd * 0.0577078016f);
            float e = exp2f(-144.26950409f * __builtin_amdgcn_rcpf(t1 + 1.f));
            if (k0 + 16 * kf + l15 > myrow + ri) e = 0.f;
            den[ri] += e;
            pw[(l4 * 4 + ri) * PLD + 16 * kf + l15] = bfhi(e);
          }
        }
        const short8 pa = *(const short8*)&pw[l15 * PLD + 8 * l4];
        __builtin_amdgcn_s_setprio(1);
        #pragma unroll
        for (int df = 0; df < 16; ++df) {
          const short8 vb = *(const short8*)&Vts[(16 * df + l15) * VLD + 8 * l4];
          acc[df] = __builtin_amdgcn_mfma_f32_16x16x32_bf16(pa, vb, acc[df], 0, 0, 0);
        }
        __builtin_amdgcn_s_setprio(0);
      }
      __builtin_amdgcn_sched_barrier(0);
      __builtin_amdgcn_s_barrier();
      __builtin_amdgcn_sched_barrier(0);
    }
    #pragma unroll
    for (int ri = 0; ri < 4; ++ri) {
      den[ri] += __shfl_xor(den[ri], 1);
      den[ri] += __shfl_xor(den[ri], 2);
      den[ri] += __shfl_xor(den[ri], 4);
      den[ri] += __shfl_xor(den[ri], 8);
    }
    if (l15 == 0) {
      #pragma unroll
      for (int ri = 0; ri < 4; ++ri)
        atomAddF(&den_g[(size_t)bh * SLEN + myrow + ri], den[ri]);
    }
    float* op = &att[((size_t)(b * SLEN + myrow)) * (NH * HD) + h * HD + l15];
    #pragma unroll
    for (int ri = 0; ri < 4; ++ri)
      #pragma unroll
      for (int df = 0; df < 16; ++df)
        atomAddF(&op[(size_t)ri * (NH * HD) + 16 * df], acc[df][ri]);
  }
}

extern "C" void kernel_launch(void* const* d_in, const int* in_sizes, int n_in,
                              void* d_out, int out_size, void* d_ws, size_t ws_size,
                              hipStream_t stream) {
  const float* hs  = (const float*)d_in[0];
  const float* fc  = (const float*)d_in[1];
  const float* fs  = (const float*)d_in[2];
  // d_in[3] = mask: pure causal, handled analytically.
  const float* WAq = (const float*)d_in[4];
  const float* WAk = (const float*)d_in[5];
  const float* WAv = (const float*)d_in[6];
  const float* WBq = (const float*)d_in[7];
  const float* WBk = (const float*)d_in[8];
  const float* WBv = (const float*)d_in[9];
  const float* Wo  = (const float*)d_in[10];
  float* out = (float*)d_out;

  // Workspace (floats), peak 127 MB. Same validated lifetime map as r22/r26/r27/r28.
  float* ws   = (float*)d_ws;
  float* Bq   = ws;
  float* Bk   = Bq + (size_t)MTOT * 1536;
  float* Bv   = Bk + (size_t)MTOT * 512;
  uint16_t* qh = (uint16_t*)(Bv + (size_t)MTOT * 512);
  uint16_t* ql = qh + (size_t)8388608;
  uint16_t* kh = ql + (size_t)8388608;
  uint16_t* vv = kh + (size_t)16777216;   // skip the unused kl slot
  float* Aall = ws + (size_t)31457280;
  float* att  = ws;
  float* den  = Bv;
  uint16_t* hsh  = (uint16_t*)(ws + (size_t)10485760);
  uint16_t* hsl  = hsh + (size_t)8388608;
  uint16_t* wfh  = (uint16_t*)(ws + (size_t)18874368);
  uint16_t* atth = (uint16_t*)(ws + (size_t)10485760);
  uint16_t* attl = atth + (size_t)8388608;
  uint16_t* wofh = (uint16_t*)(ws + (size_t)18874368);

  conv_pre<<<dim3(4096 + 2688), 256, 0, stream>>>(hs, WBq, WBk, WBv, WAq, WAk, WAv,
                                                  hsh, hsl, wfh);
  gemm_proj<<<dim3(672), 256, 0, stream>>>(hsh, hsl, wfh, Bq, Bk, Bv, Aall);
  qkv_rope<<<MTOT, 256, 0, stream>>>(Aall, Bq, Bk, Bv, fc, fs, qh, ql, kh, vv);
  zero_acc<<<8192, 256, 0, stream>>>(att, den);
  attn_mfma<<<dim3(512), 256, 0, stream>>>(qh, ql, kh, vv, att, den);
  norm_conv<<<dim3(4096 + 2048), 256, 0, stream>>>(att, den, Wo, atth, attl, wofh);
  gemm_norm<<<dim3(512), 256, 0, stream>>>(atth, attl, wofh, out);
}